// Round 1
// baseline (303.609 us; speedup 1.0000x reference)
//
#include <hip/hip_runtime.h>
#include <hip/hip_bf16.h>

typedef short bf16x8 __attribute__((ext_vector_type(8)));
typedef float f32x4 __attribute__((ext_vector_type(4)));

__device__ __forceinline__ float bf2f(ushort u) {
    union { unsigned int i; float f; } c; c.i = ((unsigned int)u) << 16; return c.f;
}
__device__ __forceinline__ ushort f2bf(float f) {
    union { float f; unsigned int i; } c; c.f = f;
    unsigned int x = c.i;
    return (ushort)((x + 0x7fffu + ((x >> 16) & 1u)) >> 16);  // RNE
}

#define GLOAD_LDS16(g, l) __builtin_amdgcn_global_load_lds( \
    (const __attribute__((address_space(1))) unsigned int*)(g), \
    (__attribute__((address_space(3))) unsigned int*)(l), 16, 0, 0)

// ---------------- prep: fp32 -> bf16 (vectorized) ----------------
__global__ __launch_bounds__(256) void k_cvt_bf16(const float* __restrict__ in,
                                                  ushort* __restrict__ out, int n4) {
    int i = blockIdx.x * 256 + threadIdx.x;
    if (i < n4) {
        float4 v = ((const float4*)in)[i];
        ushort4 o;
        o.x = f2bf(v.x); o.y = f2bf(v.y); o.z = f2bf(v.z); o.w = f2bf(v.w);
        ((ushort4*)out)[i] = o;
    }
}

// ---------------- prep: [K][N] fp32 -> [N][K] bf16 ----------------
__global__ __launch_bounds__(256) void k_transpose_cvt(const float* __restrict__ in,
                                                       ushort* __restrict__ out,
                                                       int K, int N) {
    __shared__ float tile[32][33];
    int n0 = blockIdx.x * 32, k0 = blockIdx.y * 32;
    int tx = threadIdx.x, ty = threadIdx.y;  // blockDim (32,8)
    #pragma unroll
    for (int i = 0; i < 32; i += 8)
        tile[ty + i][tx] = in[(size_t)(k0 + ty + i) * N + n0 + tx];
    __syncthreads();
    #pragma unroll
    for (int i = 0; i < 32; i += 8)
        out[(size_t)(n0 + ty + i) * K + k0 + tx] = f2bf(tile[tx][ty + i]);
}

// ---------------- GEMM: C[M][N] = A[M][K] * Bt[N][K]^T + bias ----------------
// m97 structure: 128x128 tile, BK=32, 4 waves, global_load_lds width=16.
template<bool OUT_BF16>
__global__ __launch_bounds__(256) void k_gemm_bt(const ushort* __restrict__ A,
                                                 const ushort* __restrict__ Bt,
                                                 const float* __restrict__ bias,
                                                 void* __restrict__ Cout,
                                                 int M, int N, int K) {
    __shared__ __align__(16) ushort lA[128 * 32];
    __shared__ __align__(16) ushort lB[128 * 32];
    const int tid = threadIdx.x;
    const int wave = tid >> 6, lane = tid & 63;
    const int bm = blockIdx.y * 128, bn = blockIdx.x * 128;
    const int wm = (wave >> 1) * 64, wn = (wave & 1) * 64;
    const int r = lane & 15, qd = lane >> 4;

    // staging: issue i in {0,1}: rows i*64 + wave*16 + lane/4, cols (lane&3)*8 .. +8
    const int srow = wave * 16 + (lane >> 2);
    const int scol = (lane & 3) * 8;
    const ushort* gA = A + (size_t)(bm + srow) * K + scol;
    const ushort* gB = Bt + (size_t)(bn + srow) * K + scol;

    f32x4 acc[4][4];
    #pragma unroll
    for (int m = 0; m < 4; ++m)
        #pragma unroll
        for (int n = 0; n < 4; ++n)
            acc[m][n] = (f32x4){0.f, 0.f, 0.f, 0.f};

    for (int k0 = 0; k0 < K; k0 += 32) {
        #pragma unroll
        for (int i = 0; i < 2; ++i) {
            GLOAD_LDS16(gA + (size_t)i * 64 * K + k0, lA + i * 2048 + wave * 512);
            GLOAD_LDS16(gB + (size_t)i * 64 * K + k0, lB + i * 2048 + wave * 512);
        }
        __syncthreads();
        bf16x8 af[4], bfr[4];
        #pragma unroll
        for (int m = 0; m < 4; ++m)
            af[m] = *(const bf16x8*)&lA[(wm + m * 16 + r) * 32 + qd * 8];
        #pragma unroll
        for (int n = 0; n < 4; ++n)
            bfr[n] = *(const bf16x8*)&lB[(wn + n * 16 + r) * 32 + qd * 8];
        #pragma unroll
        for (int m = 0; m < 4; ++m)
            #pragma unroll
            for (int n = 0; n < 4; ++n)
                acc[m][n] = __builtin_amdgcn_mfma_f32_16x16x32_bf16(af[m], bfr[n], acc[m][n], 0, 0, 0);
        __syncthreads();
    }

    float* Cf = (float*)Cout;
    ushort* Cb = (ushort*)Cout;
    #pragma unroll
    for (int m = 0; m < 4; ++m) {
        int row0 = bm + wm + m * 16 + qd * 4;
        #pragma unroll
        for (int n = 0; n < 4; ++n) {
            int col = bn + wn + n * 16 + r;
            float bv = bias[col];
            #pragma unroll
            for (int j = 0; j < 4; ++j) {
                float v = acc[m][n][j] + bv;
                if (OUT_BF16) Cb[(size_t)(row0 + j) * N + col] = f2bf(v);
                else          Cf[(size_t)(row0 + j) * N + col] = v;
            }
        }
    }
}

// ---------------- per-token head-mixing attention ----------------
// qkv row layout: col = h*192 + {0..63 q, 64..127 k, 128..191 v}
__global__ __launch_bounds__(256) void k_attn(const ushort* __restrict__ qkv,
                                              ushort* __restrict__ ctx) {
    __shared__ float sq[16 * 193];   // [h][192], stride 193 (bank-conflict-free)
    __shared__ float sa[16][17];
    const int t = threadIdx.x;
    const size_t tok = blockIdx.x;
    const ushort* row = qkv + tok * 3072;
    for (int i = t; i < 3072; i += 256) {
        int h = i / 192, c = i - h * 192;
        sq[h * 193 + c] = bf2f(row[i]);
    }
    __syncthreads();
    const int h = t >> 4, g = t & 15;
    const float* qp = sq + h * 193;
    const float* kp = sq + g * 193 + 64;
    float s = 0.f;
    #pragma unroll
    for (int d = 0; d < 64; ++d) s += qp[d] * kp[d];
    s *= 0.125f;
    float mx = s;
    #pragma unroll
    for (int o = 8; o; o >>= 1) mx = fmaxf(mx, __shfl_xor(mx, o, 16));
    float e = __expf(s - mx);
    float sum = e;
    #pragma unroll
    for (int o = 8; o; o >>= 1) sum += __shfl_xor(sum, o, 16);
    sa[h][g] = e / sum;
    __syncthreads();
    #pragma unroll
    for (int j = 0; j < 4; ++j) {
        int o = t + j * 256;
        int oh = o >> 6, od = o & 63;
        float c = 0.f;
        #pragma unroll
        for (int gg = 0; gg < 16; ++gg) c += sa[oh][gg] * sq[gg * 193 + 128 + od];
        ctx[tok * 1024 + o] = f2bf(c);
    }
}

extern "C" void kernel_launch(void* const* d_in, const int* in_sizes, int n_in,
                              void* d_out, int out_size, void* d_ws, size_t ws_size,
                              hipStream_t stream) {
    const float* x     = (const float*)d_in[0];
    const float* W_qkv = (const float*)d_in[1];
    const float* b_qkv = (const float*)d_in[2];
    const float* W_out = (const float*)d_in[3];
    const float* b_out = (const float*)d_in[4];

    const int M = 16384, D = 1024, N3 = 3072;

    // ws layout (bytes): xb/ctx 33.55M | wqkT 6.29M | woT 2.10M | qkv 100.66M  = 142.6 MB
    ushort* xb   = (ushort*)d_ws;
    ushort* wqkT = xb + (size_t)M * D;
    ushort* woT  = wqkT + (size_t)N3 * D;
    ushort* qkv  = woT + (size_t)D * D;
    ushort* ctx  = xb;  // xb dead after GEMM1; reuse for context

    hipLaunchKernelGGL(k_cvt_bf16, dim3((M * D / 4 + 255) / 256), dim3(256), 0, stream,
                       x, xb, M * D / 4);
    hipLaunchKernelGGL(k_transpose_cvt, dim3(N3 / 32, D / 32), dim3(32, 8), 0, stream,
                       W_qkv, wqkT, D, N3);
    hipLaunchKernelGGL(k_transpose_cvt, dim3(D / 32, D / 32), dim3(32, 8), 0, stream,
                       W_out, woT, D, D);
    hipLaunchKernelGGL((k_gemm_bt<true>), dim3(N3 / 128, M / 128), dim3(256), 0, stream,
                       xb, wqkT, b_qkv, (void*)qkv, M, N3, D);
    hipLaunchKernelGGL(k_attn, dim3(M), dim3(256), 0, stream, qkv, ctx);
    hipLaunchKernelGGL((k_gemm_bt<false>), dim3(D / 128, M / 128), dim3(256), 0, stream,
                       ctx, woT, b_out, d_out, M, D, D);
}

// Round 2
// 253.471 us; speedup vs baseline: 1.1978x; 1.1978x over previous
//
#include <hip/hip_runtime.h>
#include <hip/hip_bf16.h>

typedef short bf16x8 __attribute__((ext_vector_type(8)));
typedef float f32x4 __attribute__((ext_vector_type(4)));
typedef ushort ushort8_t __attribute__((ext_vector_type(8)));

__device__ __forceinline__ float bf2f(ushort u) {
    union { unsigned int i; float f; } c; c.i = ((unsigned int)u) << 16; return c.f;
}
__device__ __forceinline__ ushort f2bf(float f) {
    union { float f; unsigned int i; } c; c.f = f;
    unsigned int x = c.i;
    return (ushort)((x + 0x7fffu + ((x >> 16) & 1u)) >> 16);  // RNE
}

#define GLOAD_LDS16(g, l) __builtin_amdgcn_global_load_lds( \
    (const __attribute__((address_space(1))) unsigned int*)(g), \
    (__attribute__((address_space(3))) unsigned int*)(l), 16, 0, 0)

// ---------------- prep: fp32 -> bf16 (vectorized) ----------------
__global__ __launch_bounds__(256) void k_cvt_bf16(const float* __restrict__ in,
                                                  ushort* __restrict__ out, int n4) {
    int i = blockIdx.x * 256 + threadIdx.x;
    if (i < n4) {
        float4 v = ((const float4*)in)[i];
        ushort4 o;
        o.x = f2bf(v.x); o.y = f2bf(v.y); o.z = f2bf(v.z); o.w = f2bf(v.w);
        ((ushort4*)out)[i] = o;
    }
}

// ---------------- prep: [K][N] fp32 -> [N][K] bf16 ----------------
__global__ __launch_bounds__(256) void k_transpose_cvt(const float* __restrict__ in,
                                                       ushort* __restrict__ out,
                                                       int K, int N) {
    __shared__ float tile[32][33];
    int n0 = blockIdx.x * 32, k0 = blockIdx.y * 32;
    int tx = threadIdx.x, ty = threadIdx.y;  // blockDim (32,8)
    #pragma unroll
    for (int i = 0; i < 32; i += 8)
        tile[ty + i][tx] = in[(size_t)(k0 + ty + i) * N + n0 + tx];
    __syncthreads();
    #pragma unroll
    for (int i = 0; i < 32; i += 8)
        out[(size_t)(n0 + ty + i) * K + k0 + tx] = f2bf(tile[tx][ty + i]);
}

// ================= 256x256 8-phase GEMM (K=1024 fixed) =================
// C[M][N] = A[M][1024] * Bt[N][1024]^T + bias.  8 waves (2Mx4N), BK=64,
// LDS 128KB: buf{0,1} x { A[2][256][32], B[2][256][32] } bf16 (k-half regions).
// Swizzle: 16B chunk index ^= (row&3), applied on pre-swizzled global source
// (gload_lds writes linearly) and on ds_read address.  vmcnt(10) at ph2/4/6/8.

#define LDSA(c,kk) (lds + (c)*65536 + (kk)*16384)
#define LDSB(c,kk) (lds + (c)*65536 + 32768 + (kk)*16384)
#define STAGE_A(c,kk,col) do { \
    GLOAD_LDS16(gA0 + (col), LDSA(c,kk) + wave*1024); \
    GLOAD_LDS16(gA1 + (col), LDSA(c,kk) + 8192 + wave*1024); } while(0)
#define STAGE_B(c,kk,col) do { \
    GLOAD_LDS16(gB0 + (col), LDSB(c,kk) + wave*1024); \
    GLOAD_LDS16(gB1 + (col), LDSB(c,kk) + 8192 + wave*1024); } while(0)
#define READ_A8(c,kk) do { const char* _p = LDSA(c,kk) + aoff; \
    _Pragma("unroll") for (int m = 0; m < 8; ++m) af[m] = *(const bf16x8*)(_p + m*1024); } while(0)
#define READ_B2(c,kk,n0) do { const char* _p = LDSB(c,kk) + boff; \
    bfr[n0] = *(const bf16x8*)(_p + (n0)*1024); \
    bfr[(n0)+1] = *(const bf16x8*)(_p + ((n0)+1)*1024); } while(0)
#define MFMA16(n0) do { _Pragma("unroll") for (int m = 0; m < 8; ++m) { \
    acc[m][n0]     = __builtin_amdgcn_mfma_f32_16x16x32_bf16(af[m], bfr[n0],     acc[m][n0],     0,0,0); \
    acc[m][(n0)+1] = __builtin_amdgcn_mfma_f32_16x16x32_bf16(af[m], bfr[(n0)+1], acc[m][(n0)+1], 0,0,0); } } while(0)

#define BAR __builtin_amdgcn_s_barrier()
#define LGK0 asm volatile("s_waitcnt lgkmcnt(0)" ::: "memory")
#define VM10 asm volatile("s_waitcnt vmcnt(10)" ::: "memory")
#define VM0  asm volatile("s_waitcnt vmcnt(0)" ::: "memory")

#define PH(reads, stage, mf, vm) do { reads; stage; BAR; LGK0; \
    __builtin_amdgcn_s_setprio(1); mf; __builtin_amdgcn_s_setprio(0); vm; BAR; } while(0)

// One iteration: consume tiles t (buf0) and t+1 (buf1); stage Bk1(t+1),
// then tile t+2 into buf0 (ph2-5) and tile t+3 head into buf1 (ph6-8).
#define ITER(kb, LAST) do { \
    PH( { READ_A8(0,0); READ_B2(0,0,0); }, STAGE_B(1,1,(kb)+96), MFMA16(0), ); \
    PH( { READ_B2(0,0,2); }, if(!(LAST)) STAGE_A(0,0,(kb)+128), MFMA16(2), if(LAST) VM0; else VM10 ); \
    PH( { READ_A8(0,1); READ_B2(0,1,0); }, if(!(LAST)) STAGE_B(0,0,(kb)+128), MFMA16(0), ); \
    PH( { READ_B2(0,1,2); }, if(!(LAST)) STAGE_A(0,1,(kb)+160), MFMA16(2), if(!(LAST)) VM10 ); \
    PH( { READ_A8(1,0); READ_B2(1,0,0); }, if(!(LAST)) STAGE_B(0,1,(kb)+160), MFMA16(0), ); \
    PH( { READ_B2(1,0,2); }, if(!(LAST)) STAGE_A(1,0,(kb)+192), MFMA16(2), if(!(LAST)) VM10 ); \
    PH( { READ_A8(1,1); READ_B2(1,1,0); }, if(!(LAST)) STAGE_B(1,0,(kb)+192), MFMA16(0), ); \
    PH( { READ_B2(1,1,2); }, if(!(LAST)) STAGE_A(1,1,(kb)+224), MFMA16(2), if(!(LAST)) VM10 ); \
} while(0)

template<bool OUT_BF16>
__global__ __launch_bounds__(512, 2) void k_gemm256(const ushort* __restrict__ A,
                                                    const ushort* __restrict__ Bt,
                                                    const float* __restrict__ bias,
                                                    void* __restrict__ Cout,
                                                    int N, int NTN) {
    __shared__ __align__(16) char lds[131072];
    const int K = 1024;
    const int tid = threadIdx.x;
    const int wave = tid >> 6, lane = tid & 63;
    const int wr = wave >> 2, wc = wave & 3;
    const int r = lane & 15, q = lane >> 4;

    // bijective XCD swizzle (gridDim.x % 8 == 0)
    const int cpx = gridDim.x >> 3, wg = blockIdx.x;
    const int swz = (wg & 7) * cpx + (wg >> 3);
    const int tm = swz / NTN, tn = swz - tm * NTN;
    const int bm = tm * 256, bn = tn * 256;

    // staging lane pointers (source pre-swizzled: chunk ^= row&3)
    const int srow = tid >> 2;                      // 0..127
    const int c16l = (tid & 3) ^ (srow & 3);
    const ushort* gA0 = A  + (size_t)(bm + srow) * K + c16l * 8;
    const ushort* gA1 = gA0 + (size_t)128 * K;
    const ushort* gB0 = Bt + (size_t)(bn + srow) * K + c16l * 8;
    const ushort* gB1 = gB0 + (size_t)128 * K;

    // swizzled ds_read offsets
    const int chunkx = ((q ^ (r & 3)) << 4);
    const int aoff = (wr * 128 + r) * 64 + chunkx;
    const int boff = (wc * 64 + r) * 64 + chunkx;

    f32x4 acc[8][4];
    #pragma unroll
    for (int m = 0; m < 8; ++m)
        #pragma unroll
        for (int n = 0; n < 4; ++n)
            acc[m][n] = (f32x4){0.f, 0.f, 0.f, 0.f};
    bf16x8 af[8], bfr[4];

    // prologue: tile0 (all 4 halves), tile1 (Ak0,Bk0,Ak1)
    STAGE_A(0,0,0);  STAGE_B(0,0,0);
    STAGE_A(0,1,32); STAGE_B(0,1,32);
    STAGE_A(1,0,64); STAGE_B(1,0,64);
    STAGE_A(1,1,96);
    VM10; BAR;

    #pragma unroll 1
    for (int i = 0; i < 7; ++i) { ITER(i * 128, 0); }
    ITER(896, 1);

    float* Cf = (float*)Cout;
    ushort* Cb = (ushort*)Cout;
    #pragma unroll
    for (int m = 0; m < 8; ++m) {
        int row0 = bm + wr * 128 + m * 16 + q * 4;
        #pragma unroll
        for (int n = 0; n < 4; ++n) {
            int col = bn + wc * 64 + n * 16 + r;
            float bv = bias[col];
            #pragma unroll
            for (int j = 0; j < 4; ++j) {
                float v = acc[m][n][j] + bv;
                if (OUT_BF16) Cb[(size_t)(row0 + j) * N + col] = f2bf(v);
                else          Cf[(size_t)(row0 + j) * N + col] = v;
            }
        }
    }
}

// ---------------- per-token head-mixing attention ----------------
// qkv row layout: col = h*192 + {0..63 q, 64..127 k, 128..191 v}
__global__ __launch_bounds__(256) void k_attn(const ushort* __restrict__ qkv,
                                              ushort* __restrict__ ctx) {
    __shared__ float sq[16 * 193];   // [h][192], stride 193 (bank-conflict-free)
    __shared__ float sa[16][17];
    const int t = threadIdx.x;
    const size_t tok = blockIdx.x;
    const ushort* row = qkv + tok * 3072;
    #pragma unroll
    for (int j = 0; j < 2; ++j) {
        int idx = t + j * 256;            // 16B chunk index, 384 total
        if (idx < 384) {
            ushort8_t v = ((const ushort8_t*)row)[idx];
            int i = idx * 8;
            int h = i / 192, c = i - h * 192;
            float* dst = sq + h * 193 + c;
            #pragma unroll
            for (int e = 0; e < 8; ++e) dst[e] = bf2f(v[e]);
        }
    }
    __syncthreads();
    const int h = t >> 4, g = t & 15;
    const float* qp = sq + h * 193;
    const float* kp = sq + g * 193 + 64;
    float s = 0.f;
    #pragma unroll
    for (int d = 0; d < 64; ++d) s += qp[d] * kp[d];
    s *= 0.125f;
    float mx = s;
    #pragma unroll
    for (int o = 8; o; o >>= 1) mx = fmaxf(mx, __shfl_xor(mx, o, 16));
    float e = __expf(s - mx);
    float sum = e;
    #pragma unroll
    for (int o = 8; o; o >>= 1) sum += __shfl_xor(sum, o, 16);
    sa[h][g] = e / sum;
    __syncthreads();
    #pragma unroll
    for (int j = 0; j < 4; ++j) {
        int o = t + j * 256;
        int oh = o >> 6, od = o & 63;
        float c = 0.f;
        #pragma unroll
        for (int gg = 0; gg < 16; ++gg) c += sa[oh][gg] * sq[gg * 193 + 128 + od];
        ctx[tok * 1024 + o] = f2bf(c);
    }
}

extern "C" void kernel_launch(void* const* d_in, const int* in_sizes, int n_in,
                              void* d_out, int out_size, void* d_ws, size_t ws_size,
                              hipStream_t stream) {
    const float* x     = (const float*)d_in[0];
    const float* W_qkv = (const float*)d_in[1];
    const float* b_qkv = (const float*)d_in[2];
    const float* W_out = (const float*)d_in[3];
    const float* b_out = (const float*)d_in[4];

    const int M = 16384, D = 1024, N3 = 3072;

    ushort* xb   = (ushort*)d_ws;
    ushort* wqkT = xb + (size_t)M * D;
    ushort* woT  = wqkT + (size_t)N3 * D;
    ushort* qkv  = woT + (size_t)D * D;
    ushort* ctx  = xb;  // xb dead after GEMM1; reuse for context

    hipLaunchKernelGGL(k_cvt_bf16, dim3((M * D / 4 + 255) / 256), dim3(256), 0, stream,
                       x, xb, M * D / 4);
    hipLaunchKernelGGL(k_transpose_cvt, dim3(N3 / 32, D / 32), dim3(32, 8), 0, stream,
                       W_qkv, wqkT, D, N3);
    hipLaunchKernelGGL(k_transpose_cvt, dim3(D / 32, D / 32), dim3(32, 8), 0, stream,
                       W_out, woT, D, D);
    hipLaunchKernelGGL((k_gemm256<true>), dim3((N3 / 256) * (M / 256)), dim3(512), 0, stream,
                       xb, wqkT, b_qkv, (void*)qkv, N3, N3 / 256);
    hipLaunchKernelGGL(k_attn, dim3(M), dim3(256), 0, stream, qkv, ctx);
    hipLaunchKernelGGL((k_gemm256<false>), dim3((D / 256) * (M / 256)), dim3(512), 0, stream,
                       ctx, woT, b_out, d_out, D, D / 256);
}

// Round 3
// 251.292 us; speedup vs baseline: 1.2082x; 1.0087x over previous
//
#include <hip/hip_runtime.h>
#include <hip/hip_bf16.h>

typedef short bf16x8 __attribute__((ext_vector_type(8)));
typedef float f32x4 __attribute__((ext_vector_type(4)));
typedef ushort ushort8_t __attribute__((ext_vector_type(8)));

__device__ __forceinline__ float bf2f(ushort u) {
    union { unsigned int i; float f; } c; c.i = ((unsigned int)u) << 16; return c.f;
}
__device__ __forceinline__ ushort f2bf(float f) {
    union { float f; unsigned int i; } c; c.f = f;
    unsigned int x = c.i;
    return (ushort)((x + 0x7fffu + ((x >> 16) & 1u)) >> 16);  // RNE
}

#define GLOAD_LDS16(g, l) __builtin_amdgcn_global_load_lds( \
    (const __attribute__((address_space(1))) unsigned int*)(g), \
    (__attribute__((address_space(3))) unsigned int*)(l), 16, 0, 0)

// ---------------- prep: fp32 -> bf16 (vectorized) ----------------
__global__ __launch_bounds__(256) void k_cvt_bf16(const float* __restrict__ in,
                                                  ushort* __restrict__ out, int n4) {
    int i = blockIdx.x * 256 + threadIdx.x;
    if (i < n4) {
        float4 v = ((const float4*)in)[i];
        ushort4 o;
        o.x = f2bf(v.x); o.y = f2bf(v.y); o.z = f2bf(v.z); o.w = f2bf(v.w);
        ((ushort4*)out)[i] = o;
    }
}

// ---------------- prep: [K][N] fp32 -> [N][K] bf16 ----------------
__global__ __launch_bounds__(256) void k_transpose_cvt(const float* __restrict__ in,
                                                       ushort* __restrict__ out,
                                                       int K, int N) {
    __shared__ float tile[32][33];
    int n0 = blockIdx.x * 32, k0 = blockIdx.y * 32;
    int tx = threadIdx.x, ty = threadIdx.y;  // blockDim (32,8)
    #pragma unroll
    for (int i = 0; i < 32; i += 8)
        tile[ty + i][tx] = in[(size_t)(k0 + ty + i) * N + n0 + tx];
    __syncthreads();
    #pragma unroll
    for (int i = 0; i < 32; i += 8)
        out[(size_t)(n0 + ty + i) * K + k0 + tx] = f2bf(tile[tx][ty + i]);
}

// ================= 256x256 8-phase GEMM (K=1024 fixed) =================
// C[M][N] = A[M][1024] * Bt[N][1024]^T + bias.  8 waves (2Mx4N), BK=64,
// LDS 128KB: buf{0,1} x { A[2][256][32], B[2][256][32] } bf16 (k-half regions).
// Swizzle (16-lane-group conflict model): 16B chunk ^= (row>>1)&3, applied on
// pre-swizzled global source (gload_lds writes linearly) and on ds_read addr.
// Within a 16-lane read group positions 4*(r&1) + (q^((r>>1)&3)) cover all 8
// slots exactly twice -> conflict-free.  vmcnt(10) at ph2/4/6/8.

#define LDSA(c,kk) (lds + (c)*65536 + (kk)*16384)
#define LDSB(c,kk) (lds + (c)*65536 + 32768 + (kk)*16384)
#define STAGE_A(c,kk,col) do { \
    GLOAD_LDS16(gA0 + (col), LDSA(c,kk) + wave*1024); \
    GLOAD_LDS16(gA1 + (col), LDSA(c,kk) + 8192 + wave*1024); } while(0)
#define STAGE_B(c,kk,col) do { \
    GLOAD_LDS16(gB0 + (col), LDSB(c,kk) + wave*1024); \
    GLOAD_LDS16(gB1 + (col), LDSB(c,kk) + 8192 + wave*1024); } while(0)
#define READ_A8(c,kk) do { const char* _p = LDSA(c,kk) + aoff; \
    _Pragma("unroll") for (int m = 0; m < 8; ++m) af[m] = *(const bf16x8*)(_p + m*1024); } while(0)
#define READ_B2(c,kk,n0) do { const char* _p = LDSB(c,kk) + boff; \
    bfr[n0] = *(const bf16x8*)(_p + (n0)*1024); \
    bfr[(n0)+1] = *(const bf16x8*)(_p + ((n0)+1)*1024); } while(0)
#define MFMA16(n0) do { _Pragma("unroll") for (int m = 0; m < 8; ++m) { \
    acc[m][n0]     = __builtin_amdgcn_mfma_f32_16x16x32_bf16(af[m], bfr[n0],     acc[m][n0],     0,0,0); \
    acc[m][(n0)+1] = __builtin_amdgcn_mfma_f32_16x16x32_bf16(af[m], bfr[(n0)+1], acc[m][(n0)+1], 0,0,0); } } while(0)

#define BAR __builtin_amdgcn_s_barrier()
#define LGK0 asm volatile("s_waitcnt lgkmcnt(0)" ::: "memory")
#define VM10 asm volatile("s_waitcnt vmcnt(10)" ::: "memory")
#define VM0  asm volatile("s_waitcnt vmcnt(0)" ::: "memory")

#define PH(reads, stage, mf, vm) do { reads; stage; BAR; LGK0; \
    __builtin_amdgcn_s_setprio(1); mf; __builtin_amdgcn_s_setprio(0); vm; BAR; } while(0)

// One iteration: consume tiles t (buf0) and t+1 (buf1); stage Bk1(t+1),
// then tile t+2 into buf0 (ph2-5) and tile t+3 head into buf1 (ph6-8).
#define ITER(kb, LAST) do { \
    PH( { READ_A8(0,0); READ_B2(0,0,0); }, STAGE_B(1,1,(kb)+96), MFMA16(0), ); \
    PH( { READ_B2(0,0,2); }, if(!(LAST)) STAGE_A(0,0,(kb)+128), MFMA16(2), if(LAST) VM0; else VM10 ); \
    PH( { READ_A8(0,1); READ_B2(0,1,0); }, if(!(LAST)) STAGE_B(0,0,(kb)+128), MFMA16(0), ); \
    PH( { READ_B2(0,1,2); }, if(!(LAST)) STAGE_A(0,1,(kb)+160), MFMA16(2), if(!(LAST)) VM10 ); \
    PH( { READ_A8(1,0); READ_B2(1,0,0); }, if(!(LAST)) STAGE_B(0,1,(kb)+160), MFMA16(0), ); \
    PH( { READ_B2(1,0,2); }, if(!(LAST)) STAGE_A(1,0,(kb)+192), MFMA16(2), if(!(LAST)) VM10 ); \
    PH( { READ_A8(1,1); READ_B2(1,1,0); }, if(!(LAST)) STAGE_B(1,0,(kb)+192), MFMA16(0), ); \
    PH( { READ_B2(1,1,2); }, if(!(LAST)) STAGE_A(1,1,(kb)+224), MFMA16(2), if(!(LAST)) VM10 ); \
} while(0)

template<bool OUT_BF16>
__global__ __launch_bounds__(512, 2) void k_gemm256(const ushort* __restrict__ A,
                                                    const ushort* __restrict__ Bt,
                                                    const float* __restrict__ bias,
                                                    void* __restrict__ Cout,
                                                    int N, int NTN) {
    __shared__ __align__(16) char lds[131072];
    const int K = 1024;
    const int tid = threadIdx.x;
    const int wave = tid >> 6, lane = tid & 63;
    const int wr = wave >> 2, wc = wave & 3;
    const int r = lane & 15, q = lane >> 4;

    // bijective XCD swizzle (gridDim.x % 8 == 0)
    const int cpx = gridDim.x >> 3, wg = blockIdx.x;
    const int swz = (wg & 7) * cpx + (wg >> 3);
    const int tm = swz / NTN, tn = swz - tm * NTN;
    const int bm = tm * 256, bn = tn * 256;

    // staging lane pointers (source pre-swizzled: chunk ^= (row>>1)&3)
    const int srow = tid >> 2;                      // 0..127
    const int c16l = (tid & 3) ^ ((srow >> 1) & 3);
    const ushort* gA0 = A  + (size_t)(bm + srow) * K + c16l * 8;
    const ushort* gA1 = gA0 + (size_t)128 * K;
    const ushort* gB0 = Bt + (size_t)(bn + srow) * K + c16l * 8;
    const ushort* gB1 = gB0 + (size_t)128 * K;

    // swizzled ds_read offsets: chunk = q ^ ((row>>1)&3), row == r (mod 16 bases)
    const int chunkx = ((q ^ ((r >> 1) & 3)) << 4);
    const int aoff = (wr * 128 + r) * 64 + chunkx;
    const int boff = (wc * 64 + r) * 64 + chunkx;

    f32x4 acc[8][4];
    #pragma unroll
    for (int m = 0; m < 8; ++m)
        #pragma unroll
        for (int n = 0; n < 4; ++n)
            acc[m][n] = (f32x4){0.f, 0.f, 0.f, 0.f};
    bf16x8 af[8], bfr[4];

    // prologue: tile0 (all 4 halves), tile1 (Ak0,Bk0,Ak1)
    STAGE_A(0,0,0);  STAGE_B(0,0,0);
    STAGE_A(0,1,32); STAGE_B(0,1,32);
    STAGE_A(1,0,64); STAGE_B(1,0,64);
    STAGE_A(1,1,96);
    VM10; BAR;

    #pragma unroll 1
    for (int i = 0; i < 7; ++i) { ITER(i * 128, 0); }
    ITER(896, 1);

    float* Cf = (float*)Cout;
    ushort* Cb = (ushort*)Cout;
    #pragma unroll
    for (int m = 0; m < 8; ++m) {
        int row0 = bm + wr * 128 + m * 16 + q * 4;
        #pragma unroll
        for (int n = 0; n < 4; ++n) {
            int col = bn + wc * 64 + n * 16 + r;
            float bv = bias[col];
            #pragma unroll
            for (int j = 0; j < 4; ++j) {
                float v = acc[m][n][j] + bv;
                if (OUT_BF16) Cb[(size_t)(row0 + j) * N + col] = f2bf(v);
                else          Cf[(size_t)(row0 + j) * N + col] = v;
            }
        }
    }
}

// ---------------- per-token head-mixing attention ----------------
// qkv row layout: col = h*192 + {0..63 q, 64..127 k, 128..191 v}
__global__ __launch_bounds__(256) void k_attn(const ushort* __restrict__ qkv,
                                              ushort* __restrict__ ctx) {
    __shared__ float sq[16 * 193];   // [h][192], stride 193 (bank-conflict-free)
    __shared__ float sa[16][17];
    const int t = threadIdx.x;
    const size_t tok = blockIdx.x;
    const ushort* row = qkv + tok * 3072;
    #pragma unroll
    for (int j = 0; j < 2; ++j) {
        int idx = t + j * 256;            // 16B chunk index, 384 total
        if (idx < 384) {
            ushort8_t v = ((const ushort8_t*)row)[idx];
            int i = idx * 8;
            int h = i / 192, c = i - h * 192;
            float* dst = sq + h * 193 + c;
            #pragma unroll
            for (int e = 0; e < 8; ++e) dst[e] = bf2f(v[e]);
        }
    }
    __syncthreads();
    const int h = t >> 4, g = t & 15;
    const float* qp = sq + h * 193;
    const float* kp = sq + g * 193 + 64;
    float s = 0.f;
    #pragma unroll
    for (int d = 0; d < 64; ++d) s += qp[d] * kp[d];
    s *= 0.125f;
    float mx = s;
    #pragma unroll
    for (int o = 8; o; o >>= 1) mx = fmaxf(mx, __shfl_xor(mx, o, 16));
    float e = __expf(s - mx);
    float sum = e;
    #pragma unroll
    for (int o = 8; o; o >>= 1) sum += __shfl_xor(sum, o, 16);
    sa[h][g] = e / sum;
    __syncthreads();
    #pragma unroll
    for (int j = 0; j < 4; ++j) {
        int o = t + j * 256;
        int oh = o >> 6, od = o & 63;
        float c = 0.f;
        #pragma unroll
        for (int gg = 0; gg < 16; ++gg) c += sa[oh][gg] * sq[gg * 193 + 128 + od];
        ctx[tok * 1024 + o] = f2bf(c);
    }
}

extern "C" void kernel_launch(void* const* d_in, const int* in_sizes, int n_in,
                              void* d_out, int out_size, void* d_ws, size_t ws_size,
                              hipStream_t stream) {
    const float* x     = (const float*)d_in[0];
    const float* W_qkv = (const float*)d_in[1];
    const float* b_qkv = (const float*)d_in[2];
    const float* W_out = (const float*)d_in[3];
    const float* b_out = (const float*)d_in[4];

    const int M = 16384, D = 1024, N3 = 3072;

    ushort* xb   = (ushort*)d_ws;
    ushort* wqkT = xb + (size_t)M * D;
    ushort* woT  = wqkT + (size_t)N3 * D;
    ushort* qkv  = woT + (size_t)D * D;
    ushort* ctx  = xb;  // xb dead after GEMM1; reuse for context

    hipLaunchKernelGGL(k_cvt_bf16, dim3((M * D / 4 + 255) / 256), dim3(256), 0, stream,
                       x, xb, M * D / 4);
    hipLaunchKernelGGL(k_transpose_cvt, dim3(N3 / 32, D / 32), dim3(32, 8), 0, stream,
                       W_qkv, wqkT, D, N3);
    hipLaunchKernelGGL(k_transpose_cvt, dim3(D / 32, D / 32), dim3(32, 8), 0, stream,
                       W_out, woT, D, D);
    hipLaunchKernelGGL((k_gemm256<true>), dim3((N3 / 256) * (M / 256)), dim3(512), 0, stream,
                       xb, wqkT, b_qkv, (void*)qkv, N3, N3 / 256);
    hipLaunchKernelGGL(k_attn, dim3(M), dim3(256), 0, stream, qkv, ctx);
    hipLaunchKernelGGL((k_gemm256<false>), dim3((D / 256) * (M / 256)), dim3(512), 0, stream,
                       ctx, woT, b_out, d_out, D, D / 256);
}